// Round 2
// baseline (96.332 us; speedup 1.0000x reference)
//
#include <hip/hip_runtime.h>

#define NAG  8192
#define JCH  128            // j's per block (one LDS chunk)
#define NCH  (NAG / JCH)    // 64 j-chunks
#define IBLK 1024           // i's per block = 256 threads * 4
#define GG   36
#define HID  128

// Per-pair body: rx/ry arithmetic identical to the v1 kernel (absmax == 0.0).
// Bit layout: cell (a,b) -> bit a*8+b (a,b in [0,6)); rows/cols 6,7 and bit 63
// are dead (never read by kernel 2).
#define PAIR(QX, QY, BX, BY, M)                                          \
  {                                                                      \
    const float rx = (QX) + (BX);                                        \
    const float ry = (QY) + (BY);                                        \
    const int ix = (int)rx; /* trunc==floor on valid range */            \
    const int iy = (int)ry;                                              \
    const bool v = (rx >= 0.0f) & (ry >= 0.0f) &                         \
                   ((unsigned)ix < 6u) & ((unsigned)iy < 6u);            \
    const int bp = v ? (((ix & 7) << 3) | (iy & 7)) : 63;                \
    (M) |= (1ull << bp);                                                 \
  }

#define PAIR_NS(QX, QY, BX, BY, M, J, I)                                 \
  {                                                                      \
    const float rx = (QX) + (BX);                                        \
    const float ry = (QY) + (BY);                                        \
    const int ix = (int)rx;                                              \
    const int iy = (int)ry;                                              \
    const bool v = (rx >= 0.0f) & (ry >= 0.0f) &                         \
                   ((unsigned)ix < 6u) & ((unsigned)iy < 6u) &           \
                   ((J) != (I));                                         \
    const int bp = v ? (((ix & 7) << 3) | (iy & 7)) : 63;                \
    (M) |= (1ull << bp);                                                 \
  }

// Kernel 1: partial occupancy bitmasks. Grid (8, 64): block = 1024 i's x 128 j's.
// Each thread owns 4 consecutive agents -> LDS j-read amortized 4x.
__global__ __launch_bounds__(256) void occ_pair_masks(
    const float* __restrict__ obs, unsigned long long* __restrict__ partials) {
  const int t  = threadIdx.x;
  const int bx = blockIdx.x, by = blockIdx.y;
  const int i0 = bx * IBLK + t * 4;
  const int jbase = by * JCH;

  __shared__ float2 pj[JCH];
  if (t < JCH) {
    const float2 q = ((const float2*)obs)[jbase + t];
    pj[t] = make_float2(q.x * 2.0f, q.y * 2.0f);
  }

  const float4* obs4 = (const float4*)obs;
  const float4 A = obs4[i0 / 2];
  const float4 B = obs4[i0 / 2 + 1];
  const float bx0 = 3.0f - A.x * 2.0f, by0 = 3.0f - A.y * 2.0f;
  const float bx1 = 3.0f - A.z * 2.0f, by1 = 3.0f - A.w * 2.0f;
  const float bx2 = 3.0f - B.x * 2.0f, by2 = 3.0f - B.y * 2.0f;
  const float bx3 = 3.0f - B.z * 2.0f, by3 = 3.0f - B.w * 2.0f;

  __syncthreads();

  unsigned long long m0 = 0, m1 = 0, m2 = 0, m3 = 0;

  if ((by >> 3) != bx) {            // off-diagonal: no self possible (uniform branch)
    #pragma unroll 4
    for (int jj = 0; jj < JCH; ++jj) {
      const float qx = pj[jj].x, qy = pj[jj].y;
      PAIR(qx, qy, bx0, by0, m0)
      PAIR(qx, qy, bx1, by1, m1)
      PAIR(qx, qy, bx2, by2, m2)
      PAIR(qx, qy, bx3, by3, m3)
    }
  } else {                          // diagonal block: exclude self per pair
    #pragma unroll 4
    for (int jj = 0; jj < JCH; ++jj) {
      const float qx = pj[jj].x, qy = pj[jj].y;
      const int j = jbase + jj;
      PAIR_NS(qx, qy, bx0, by0, m0, j, i0 + 0)
      PAIR_NS(qx, qy, bx1, by1, m1, j, i0 + 1)
      PAIR_NS(qx, qy, bx2, by2, m2, j, i0 + 2)
      PAIR_NS(qx, qy, bx3, by3, m3, j, i0 + 3)
    }
  }

  unsigned long long* p = partials + (size_t)by * NAG + i0;
  p[0] = m0; p[1] = m1; p[2] = m2; p[3] = m3;
}

// Kernel 2: OR-reduce 64 partials per agent, then out[i] = b + sum_{set cells} W[cell].
// Block = 256 threads = 8 agents x 32 lanes; lane owns 4 consecutive output cols.
__global__ __launch_bounds__(256) void occ_matmul(
    const unsigned long long* __restrict__ partials,
    const float* __restrict__ W, const float* __restrict__ b,
    float* __restrict__ out) {
  const int t     = threadIdx.x;
  const int lane  = t & 31;
  const int agent = blockIdx.x * 8 + (t >> 5);

  unsigned long long m = partials[(size_t)lane * NAG + agent] |
                         partials[(size_t)(lane + 32) * NAG + agent];
  #pragma unroll
  for (int s = 16; s; s >>= 1) m |= __shfl_xor(m, s, 32);

  const unsigned mlo = (unsigned)m;
  const unsigned mhi = (unsigned)(m >> 32);

  const float4* W4 = (const float4*)W;      // 18 KB, L1/L2 resident
  float4 acc = ((const float4*)b)[lane];

  #pragma unroll
  for (int c = 0; c < GG; ++c) {
    const int bit = (c / 6) * 8 + (c % 6);  // compile-time remap to stride-8 bits
    const unsigned sel =
        (bit < 32) ? ((mlo >> bit) & 1u) : ((mhi >> (bit - 32)) & 1u);
    const float s = (float)sel;
    const float4 w = W4[c * 32 + lane];
    acc.x = fmaf(s, w.x, acc.x);
    acc.y = fmaf(s, w.y, acc.y);
    acc.z = fmaf(s, w.z, acc.z);
    acc.w = fmaf(s, w.w, acc.w);
  }
  ((float4*)out)[agent * 32 + lane] = acc;
}

extern "C" void kernel_launch(void* const* d_in, const int* in_sizes, int n_in,
                              void* d_out, int out_size, void* d_ws, size_t ws_size,
                              hipStream_t stream) {
  const float* obs = (const float*)d_in[0];   // [8192, 2] f32
  const float* W   = (const float*)d_in[1];   // [36, 128] f32
  const float* b   = (const float*)d_in[2];   // [128] f32
  float* out = (float*)d_out;                 // [8192, 128] f32
  unsigned long long* partials = (unsigned long long*)d_ws;  // 64*8192*8B = 4 MB

  occ_pair_masks<<<dim3(NAG / IBLK, NCH), 256, 0, stream>>>(obs, partials);
  occ_matmul<<<dim3(NAG / 8), 256, 0, stream>>>(partials, W, b, out);
}

// Round 3
// 86.078 us; speedup vs baseline: 1.1191x; 1.1191x over previous
//
#include <hip/hip_runtime.h>

#define NAG  8192
#define JCH  128            // j's per block (one LDS chunk)
#define NCH  (NAG / JCH)    // 64 j-chunks
#define IBLK 1024           // i's per block = 256 threads * 4
#define GG   36
#define HID  128

// Per-pair body, branchless, no compares:
//   rc = med3(r, -2.0, 7.5)  -> floor(rc) in {-2..7}
//   bp = (ix<<3)+iy, used mod 64 (v_lshlrev_b64 masks shift to 6 bits).
// For any ix or iy outside [0,6), bp&63 lands on row 6/7 or col 6/7 bits,
// which kernel 2 never reads. Valid cells map to bit ix*8+iy. floor (not
// trunc) correctly rejects r in (-1,0). ~10-12 VALU per pair.
#define PAIR(QX, QY, BX, BY, M)                                          \
  {                                                                      \
    const float rx = __builtin_amdgcn_fmed3f((QX) + (BX), -2.0f, 7.5f);  \
    const float ry = __builtin_amdgcn_fmed3f((QY) + (BY), -2.0f, 7.5f);  \
    const int ix = (int)floorf(rx);                                      \
    const int iy = (int)floorf(ry);                                      \
    const int bp = ((ix << 3) + iy) & 63;                                \
    (M) |= (1ull << bp);                                                 \
  }

#define PAIR_NS(QX, QY, BX, BY, M, J, I)                                 \
  {                                                                      \
    const float rx = __builtin_amdgcn_fmed3f((QX) + (BX), -2.0f, 7.5f);  \
    const float ry = __builtin_amdgcn_fmed3f((QY) + (BY), -2.0f, 7.5f);  \
    const int ix = (int)floorf(rx);                                      \
    const int iy = (int)floorf(ry);                                      \
    int bp = ((ix << 3) + iy) & 63;                                      \
    bp = ((J) != (I)) ? bp : 63;    /* self -> dead bit */               \
    (M) |= (1ull << bp);                                                 \
  }

// Kernel 1: partial occupancy bitmasks. Grid (8, 64): block = 1024 i's x 128 j's.
// Each thread owns 4 consecutive agents -> LDS j-read amortized 4x.
__global__ __launch_bounds__(256) void occ_pair_masks(
    const float* __restrict__ obs, unsigned long long* __restrict__ partials) {
  const int t  = threadIdx.x;
  const int bx = blockIdx.x, by = blockIdx.y;
  const int i0 = bx * IBLK + t * 4;
  const int jbase = by * JCH;

  __shared__ float2 pj[JCH];
  if (t < JCH) {
    const float2 q = ((const float2*)obs)[jbase + t];
    pj[t] = make_float2(q.x * 2.0f, q.y * 2.0f);
  }

  const float4* obs4 = (const float4*)obs;
  const float4 A = obs4[i0 / 2];
  const float4 B = obs4[i0 / 2 + 1];
  const float bx0 = 3.0f - A.x * 2.0f, by0 = 3.0f - A.y * 2.0f;
  const float bx1 = 3.0f - A.z * 2.0f, by1 = 3.0f - A.w * 2.0f;
  const float bx2 = 3.0f - B.x * 2.0f, by2 = 3.0f - B.y * 2.0f;
  const float bx3 = 3.0f - B.z * 2.0f, by3 = 3.0f - B.w * 2.0f;

  __syncthreads();

  unsigned long long m0 = 0, m1 = 0, m2 = 0, m3 = 0;

  if ((by >> 3) != bx) {            // off-diagonal: no self possible (uniform branch)
    #pragma unroll 4
    for (int jj = 0; jj < JCH; ++jj) {
      const float qx = pj[jj].x, qy = pj[jj].y;
      PAIR(qx, qy, bx0, by0, m0)
      PAIR(qx, qy, bx1, by1, m1)
      PAIR(qx, qy, bx2, by2, m2)
      PAIR(qx, qy, bx3, by3, m3)
    }
  } else {                          // diagonal block: exclude self per pair
    #pragma unroll 4
    for (int jj = 0; jj < JCH; ++jj) {
      const float qx = pj[jj].x, qy = pj[jj].y;
      const int j = jbase + jj;
      PAIR_NS(qx, qy, bx0, by0, m0, j, i0 + 0)
      PAIR_NS(qx, qy, bx1, by1, m1, j, i0 + 1)
      PAIR_NS(qx, qy, bx2, by2, m2, j, i0 + 2)
      PAIR_NS(qx, qy, bx3, by3, m3, j, i0 + 3)
    }
  }

  unsigned long long* p = partials + (size_t)by * NAG + i0;
  p[0] = m0; p[1] = m1; p[2] = m2; p[3] = m3;
}

// Kernel 2: OR-reduce 64 partials per agent, then out[i] = b + sum_{set cells} W[cell].
// Block = 256 threads = 8 agents x 32 lanes; lane owns 4 consecutive output cols.
__global__ __launch_bounds__(256) void occ_matmul(
    const unsigned long long* __restrict__ partials,
    const float* __restrict__ W, const float* __restrict__ b,
    float* __restrict__ out) {
  const int t     = threadIdx.x;
  const int lane  = t & 31;
  const int agent = blockIdx.x * 8 + (t >> 5);

  unsigned long long m = partials[(size_t)lane * NAG + agent] |
                         partials[(size_t)(lane + 32) * NAG + agent];
  #pragma unroll
  for (int s = 16; s; s >>= 1) m |= __shfl_xor(m, s, 32);

  const unsigned mlo = (unsigned)m;
  const unsigned mhi = (unsigned)(m >> 32);

  const float4* W4 = (const float4*)W;      // 18 KB, L1/L2 resident
  float4 acc = ((const float4*)b)[lane];

  #pragma unroll
  for (int c = 0; c < GG; ++c) {
    const int bit = (c / 6) * 8 + (c % 6);  // compile-time remap to stride-8 bits
    const unsigned sel =
        (bit < 32) ? ((mlo >> bit) & 1u) : ((mhi >> (bit - 32)) & 1u);
    const float s = (float)sel;
    const float4 w = W4[c * 32 + lane];
    acc.x = fmaf(s, w.x, acc.x);
    acc.y = fmaf(s, w.y, acc.y);
    acc.z = fmaf(s, w.z, acc.z);
    acc.w = fmaf(s, w.w, acc.w);
  }
  ((float4*)out)[agent * 32 + lane] = acc;
}

extern "C" void kernel_launch(void* const* d_in, const int* in_sizes, int n_in,
                              void* d_out, int out_size, void* d_ws, size_t ws_size,
                              hipStream_t stream) {
  const float* obs = (const float*)d_in[0];   // [8192, 2] f32
  const float* W   = (const float*)d_in[1];   // [36, 128] f32
  const float* b   = (const float*)d_in[2];   // [128] f32
  float* out = (float*)d_out;                 // [8192, 128] f32
  unsigned long long* partials = (unsigned long long*)d_ws;  // 64*8192*8B = 4 MB

  occ_pair_masks<<<dim3(NAG / IBLK, NCH), 256, 0, stream>>>(obs, partials);
  occ_matmul<<<dim3(NAG / 8), 256, 0, stream>>>(partials, W, b, out);
}